// Round 6
// baseline (96283.929 us; speedup 1.0000x reference)
//
#include <hip/hip_runtime.h>

#define NNODE 101
#define DIM   128
#define NHEAD 8
#define NSTEP 150
#define BTOT  2048
#define ENCP  132          // padded enc row stride in LDS

#define OFF_MK  16896
#define OFF_FT  33280
#define NORM_PROB 0.08838834764831845f

// One block = TWO batch elements, 512 threads (8 waves). enc slices in LDS.
// Quads (wave pairs) persist weight rows in registers: q0 fc, q1 fc1(+F stream), q2 mw, q3 mv.
// All reduction chains keep R5's proven sequential order (bit-exact).
struct __align__(16) BS {
  float enc[2][NNODE * ENCP];           // 2 x 53328 B
  float in_[2][DIM], pl[2][DIM], dec[2][DIM], q[2][DIM], attn[2][DIM], op[2][DIM];
  float U[2][1888];                     // QK/ZR: h*132+i ; CMP: 1056+h*104+n
  float sc[2][1212];                    // SC: n*12+h ; SRED: n*12+k
  float c2[2][NNODE];
  float mask[2][NNODE], mask1[2][NNODE], dem[2][NNODE];
  float cap[2], lp[2];
  int   idx[2];
};

#define EL(e,n,i)     S.enc[e][(n)*ENCP + (i)]
#define QK(e,h,i)     S.U[e][(h)*132 + (i)]
#define ZR(e,h,i)     S.U[e][(h)*132 + (i)]
#define CMP(e,h,n)    S.U[e][1056 + (h)*104 + (n)]
#define SC(e,n,h)     S.sc[e][(n)*12 + (h)]
#define SRED(e,n,k)   S.sc[e][(n)*12 + (k)]

// ws: [0,16896) fc rows padded to 132; [OFF_MK,+16384) mk repacked (h*128+j)*16+k;
// [OFF_FT,+16384) F^T rows: wsFT[j*128+i2] = sum_d mfc[d][i2]*pk[d][j]
__global__ void prep_weights(const float* __restrict__ fc_w,
                             const float* __restrict__ mk_w,
                             const float* __restrict__ mfc_w,
                             const float* __restrict__ pk_w,
                             float* __restrict__ ws) {
  int x = blockIdx.x * 256 + threadIdx.x;
  if (x < 16896) {
    int jj = x / 132, i = x - jj * 132;
    ws[x] = (i < 129) ? fc_w[jj * 129 + i] : 0.f;
    return;
  }
  x -= 16896;
  if (x < 16384) {
    int h = x >> 11, r = x & 2047, jj = r >> 4, k = r & 15;
    ws[OFF_MK + x] = mk_w[(h * 16 + k) * 128 + jj];
    return;
  }
  x -= 16384;
  if (x < 16384) {
    int jj = x >> 7, i2 = x & 127;
    float acc = 0.f;
    for (int d = 0; d < 128; ++d)
      acc = fmaf(mfc_w[d * 128 + i2], pk_w[d * 128 + jj], acc);
    ws[OFF_FT + x] = acc;
  }
}

__global__ __launch_bounds__(512, 2) void decoder_loop(
    const float* __restrict__ enc, const float* __restrict__ pool,
    const float* __restrict__ capcity, const float* __restrict__ demand,
    const float* __restrict__ fc1_w, const float* __restrict__ mw_w,
    const float* __restrict__ mv_w,
    const float* __restrict__ ws, float* __restrict__ d_out) {
  __shared__ BS S;

  const int tl   = threadIdx.x;       // 0..511
  const int j    = tl & 127;
  const int quad = tl >> 7;           // 0..3, wave-uniform
  const int e    = quad >> 1;         // elem for common (enc) phases
  const int sub  = tl & 255;          // 0..255 within elem group
  const int b    = blockIdx.x;
  const int myb  = 2 * b + e;
  const float NEG_INF = -__builtin_inff();
  const float cap0 = capcity[0];

  // ---- persistent weight registers ----
  const float* rowsrc = (quad == 0) ? ws + (size_t)j * 132
                      : (quad == 1) ? fc1_w + (size_t)j * 128
                      : (quad == 2) ? mw_w + (size_t)j * 128
                                    : mv_w + (size_t)j * 128;
  float wrow[128];
  {
    const float4* r4 = (const float4*)rowsrc;
    #pragma unroll
    for (int t = 0; t < 32; ++t) {
      float4 v = r4[t];
      wrow[4*t] = v.x; wrow[4*t+1] = v.y; wrow[4*t+2] = v.z; wrow[4*t+3] = v.w;
    }
  }
  const float wcap = (quad == 0) ? ws[(size_t)j * 132 + 128] : 0.f;
  const int hg = quad >> 1;           // PH2b head group (0: h0-3, 1: h4-7)
  const int em = quad & 1;            // PH2b elem
  float wmk[64];
  {
    #pragma unroll
    for (int hh = 0; hh < 4; ++hh) {
      const float4* m4 = (const float4*)(ws + OFF_MK + (size_t)((hg * 4 + hh) * 128 + j) * 16);
      #pragma unroll
      for (int t = 0; t < 4; ++t) {
        float4 v = m4[t];
        wmk[hh*16+4*t] = v.x; wmk[hh*16+4*t+1] = v.y; wmk[hh*16+4*t+2] = v.z; wmk[hh*16+4*t+3] = v.w;
      }
    }
  }

  // ---- stage both enc slices into LDS ----
  for (int ee = 0; ee < 2; ++ee) {
    const float* src = enc + (size_t)(2 * b + ee) * NNODE * DIM;
    for (int x = tl; x < NNODE * 32; x += 512) {
      int n = x >> 5, c = x & 31;
      *(float4*)&EL(ee, n, c * 4) = *(const float4*)(src + (size_t)n * DIM + c * 4);
    }
  }
  __syncthreads();

  // ---- init carry ----
  if (sub < 128) {
    S.in_[e][sub] = EL(e, 0, sub);
    S.pl[e][sub]  = pool[(size_t)myb * DIM + sub];
  }
  if (sub < NNODE) S.dem[e][sub] = demand[(size_t)myb * NNODE + sub];
  if (sub == 0) { S.cap[e] = capcity[myb]; S.lp[e] = 0.f; S.idx[e] = 0; }
  __syncthreads();
  if (sub < NNODE) {
    float v1 = (sub == 0) ? 1.f : 0.f;
    S.mask1[e][sub] = v1;
    S.mask[e][sub] = (S.dem[e][sub] > S.cap[e]) ? 1.f : v1;
  }
  __syncthreads();
  if (sub < 64) {                       // waves 0 (e0) and 4 (e1), full waves
    bool ok = (sub == 0) || (S.mask[e][sub] > 0.5f);
    if (sub + 64 < NNODE) ok = ok && (S.mask[e][sub + 64] > 0.5f);
    bool alld = __all(ok);
    if (alld && sub == 0) S.mask[e][0] = 0.f;
  }
  __syncthreads();

  for (int step = 0; step < NSTEP; ++step) {
    const float capR0 = S.cap[0], capR1 = S.cap[1];

    // PH1: q0: fc chains (both elems); q1: fc1 chains (both elems)
    float A0 = 0.f, A1 = 0.f;
    if (quad == 0) {
      const float4* x0 = (const float4*)&S.in_[0][0];
      const float4* x1 = (const float4*)&S.in_[1][0];
      #pragma unroll
      for (int t = 0; t < 32; ++t) {
        float4 v0 = x0[t], v1 = x1[t];
        A0 = fmaf(v0.x, wrow[4*t],   A0); A0 = fmaf(v0.y, wrow[4*t+1], A0);
        A0 = fmaf(v0.z, wrow[4*t+2], A0); A0 = fmaf(v0.w, wrow[4*t+3], A0);
        A1 = fmaf(v1.x, wrow[4*t],   A1); A1 = fmaf(v1.y, wrow[4*t+1], A1);
        A1 = fmaf(v1.z, wrow[4*t+2], A1); A1 = fmaf(v1.w, wrow[4*t+3], A1);
      }
      A0 = fmaf(capR0, wcap, A0);
      A1 = fmaf(capR1, wcap, A1);
    } else if (quad == 1) {
      const float4* x0 = (const float4*)&S.pl[0][0];
      const float4* x1 = (const float4*)&S.pl[1][0];
      #pragma unroll
      for (int t = 0; t < 32; ++t) {
        float4 v0 = x0[t], v1 = x1[t];
        A0 = fmaf(v0.x, wrow[4*t],   A0); A0 = fmaf(v0.y, wrow[4*t+1], A0);
        A0 = fmaf(v0.z, wrow[4*t+2], A0); A0 = fmaf(v0.w, wrow[4*t+3], A0);
        A1 = fmaf(v1.x, wrow[4*t],   A1); A1 = fmaf(v1.y, wrow[4*t+1], A1);
        A1 = fmaf(v1.z, wrow[4*t+2], A1); A1 = fmaf(v1.w, wrow[4*t+3], A1);
      }
    }
    __syncthreads();
    if (quad == 0)      { S.dec[0][j] = A0; S.dec[1][j] = A1; }
    else if (quad == 1) { S.pl[0][j]  = A0; S.pl[1][j]  = A1; }
    __syncthreads();

    // PH2: q2: Q = (dec+pl) @ mw^T, both elems
    if (quad == 2) {
      const float4* d0 = (const float4*)&S.dec[0][0];
      const float4* p0 = (const float4*)&S.pl[0][0];
      const float4* d1 = (const float4*)&S.dec[1][0];
      const float4* p1 = (const float4*)&S.pl[1][0];
      float B0 = 0.f, B1 = 0.f;
      #pragma unroll
      for (int t = 0; t < 32; ++t) {
        float4 a0 = d0[t], b0 = p0[t], a1 = d1[t], b1 = p1[t];
        B0 = fmaf(a0.x + b0.x, wrow[4*t],   B0); B0 = fmaf(a0.y + b0.y, wrow[4*t+1], B0);
        B0 = fmaf(a0.z + b0.z, wrow[4*t+2], B0); B0 = fmaf(a0.w + b0.w, wrow[4*t+3], B0);
        B1 = fmaf(a1.x + b1.x, wrow[4*t],   B1); B1 = fmaf(a1.y + b1.y, wrow[4*t+1], B1);
        B1 = fmaf(a1.z + b1.z, wrow[4*t+2], B1); B1 = fmaf(a1.w + b1.w, wrow[4*t+3], B1);
      }
      S.q[0][j] = B0; S.q[1][j] = B1;
    }
    __syncthreads();

    // PH2b: quad -> (elem em, heads hg*4..hg*4+3), mk from registers
    {
      const float4* q4 = (const float4*)&S.q[em][0];
      #pragma unroll
      for (int hh = 0; hh < 4; ++hh) {
        int h = hg * 4 + hh;
        float4 qa = q4[h*4], qb = q4[h*4+1], qc = q4[h*4+2], qd4 = q4[h*4+3];
        float acc = 0.f;
        acc = fmaf(qa.x,  wmk[hh*16+0],  acc); acc = fmaf(qa.y,  wmk[hh*16+1],  acc);
        acc = fmaf(qa.z,  wmk[hh*16+2],  acc); acc = fmaf(qa.w,  wmk[hh*16+3],  acc);
        acc = fmaf(qb.x,  wmk[hh*16+4],  acc); acc = fmaf(qb.y,  wmk[hh*16+5],  acc);
        acc = fmaf(qb.z,  wmk[hh*16+6],  acc); acc = fmaf(qb.w,  wmk[hh*16+7],  acc);
        acc = fmaf(qc.x,  wmk[hh*16+8],  acc); acc = fmaf(qc.y,  wmk[hh*16+9],  acc);
        acc = fmaf(qc.z,  wmk[hh*16+10], acc); acc = fmaf(qc.w,  wmk[hh*16+11], acc);
        acc = fmaf(qd4.x, wmk[hh*16+12], acc); acc = fmaf(qd4.y, wmk[hh*16+13], acc);
        acc = fmaf(qd4.z, wmk[hh*16+14], acc); acc = fmaf(qd4.w, wmk[hh*16+15], acc);
        QK(em, h, j) = acc;
      }
    }
    __syncthreads();

    // PH3: comp[h][n] = 0.25 * enc[n].qk[h]   (per-elem mapping identical to R5)
    {
      int h = sub & 7, nb = sub >> 3;   // nb 0..31
      float acc[4] = {0.f, 0.f, 0.f, 0.f};
      for (int i4 = 0; i4 < 32; ++i4) {
        float4 qv = *(const float4*)&QK(e, h, i4 * 4);
        #pragma unroll
        for (int p = 0; p < 4; ++p) {
          int n = p * 32 + nb;
          if (n < NNODE) {
            float4 e4 = *(const float4*)&EL(e, n, i4 * 4);
            acc[p] = fmaf(e4.x, qv.x, acc[p]);
            acc[p] = fmaf(e4.y, qv.y, acc[p]);
            acc[p] = fmaf(e4.z, qv.z, acc[p]);
            acc[p] = fmaf(e4.w, qv.w, acc[p]);
          }
        }
      }
      #pragma unroll
      for (int p = 0; p < 4; ++p) {
        int n = p * 32 + nb;
        if (n < NNODE)
          CMP(e, h, n) = (S.mask[e][n] > 0.5f) ? NEG_INF : 0.25f * acc[p];
      }
    }
    __syncthreads();

    // PH4: softmax; 8 waves = (elem, head pair)
    {
      int w = tl >> 6, lane = tl & 63;
      int ee = w >> 2, hb = (w & 3) * 2;
      #pragma unroll
      for (int hh = 0; hh < 2; ++hh) {
        int h = hb + hh;
        float v0 = CMP(ee, h, lane);
        float v1 = (lane < NNODE - 64) ? CMP(ee, h, lane + 64) : NEG_INF;
        float m = fmaxf(v0, v1);
        #pragma unroll
        for (int o = 32; o > 0; o >>= 1) m = fmaxf(m, __shfl_xor(m, o, 64));
        float e0 = expf(v0 - m);
        float e1 = (lane < NNODE - 64) ? expf(v1 - m) : 0.f;
        float ss = e0 + e1;
        #pragma unroll
        for (int o = 32; o > 0; o >>= 1) ss += __shfl_xor(ss, o, 64);
        SC(ee, lane, h) = e0 / ss;
        if (lane < NNODE - 64) SC(ee, lane + 64, h) = e1 / ss;
      }
    }
    __syncthreads();

    // PH5: z[h][j] = sum_n sc[n][h]*enc[n][j] — per elem, 4 heads per thread
    {
      int hb = (sub >> 7) * 4;
      float acc[4] = {0.f, 0.f, 0.f, 0.f};
      #pragma unroll 4
      for (int n = 0; n < NNODE; ++n) {
        float4 s = *(const float4*)&SC(e, n, hb);
        float ev = EL(e, n, j);
        acc[0] = fmaf(s.x, ev, acc[0]);
        acc[1] = fmaf(s.y, ev, acc[1]);
        acc[2] = fmaf(s.z, ev, acc[2]);
        acc[3] = fmaf(s.w, ev, acc[3]);
      }
      #pragma unroll
      for (int hh = 0; hh < 4; ++hh) ZR(e, hb + hh, j) = acc[hh];
    }
    __syncthreads();

    // PH5b: q3: attn chains (both elems); q1: prefetch F chunks 0,1
    float4 fb[2][4];
    if (quad == 1) {
      const float4* fsrc = (const float4*)(ws + OFF_FT + (size_t)j * 128);
      #pragma unroll
      for (int t = 0; t < 4; ++t) fb[0][t] = fsrc[t];
      #pragma unroll
      for (int t = 0; t < 4; ++t) fb[1][t] = fsrc[4 + t];
    }
    if (quad == 3) {
      int h = j >> 4;
      float C0 = 0.f, C1 = 0.f;
      #pragma unroll
      for (int t = 0; t < 32; ++t) {
        float4 z0 = *(const float4*)&ZR(0, h, t * 4);
        float4 z1 = *(const float4*)&ZR(1, h, t * 4);
        C0 = fmaf(z0.x, wrow[4*t],   C0); C0 = fmaf(z0.y, wrow[4*t+1], C0);
        C0 = fmaf(z0.z, wrow[4*t+2], C0); C0 = fmaf(z0.w, wrow[4*t+3], C0);
        C1 = fmaf(z1.x, wrow[4*t],   C1); C1 = fmaf(z1.y, wrow[4*t+1], C1);
        C1 = fmaf(z1.z, wrow[4*t+2], C1); C1 = fmaf(z1.w, wrow[4*t+3], C1);
      }
      S.attn[0][j] = C0; S.attn[1][j] = C1;
    }
    __syncthreads();

    // PH6: q1: op = attn @ F (both elems), double-buffered 16-float chunks
    if (quad == 1) {
      const float4* fsrc = (const float4*)(ws + OFF_FT + (size_t)j * 128);
      const float4* xa = (const float4*)&S.attn[0][0];
      const float4* xb = (const float4*)&S.attn[1][0];
      float D0 = 0.f, D1 = 0.f;
      #pragma unroll
      for (int c = 0; c < 8; ++c) {
        float4 f0 = fb[c & 1][0], f1 = fb[c & 1][1], f2 = fb[c & 1][2], f3 = fb[c & 1][3];
        if (c + 2 < 8) {
          #pragma unroll
          for (int t = 0; t < 4; ++t) fb[c & 1][t] = fsrc[(c + 2) * 4 + t];
        }
        float4 va, vb;
        va = xa[c*4+0]; vb = xb[c*4+0];
        D0 = fmaf(va.x, f0.x, D0); D0 = fmaf(va.y, f0.y, D0); D0 = fmaf(va.z, f0.z, D0); D0 = fmaf(va.w, f0.w, D0);
        D1 = fmaf(vb.x, f0.x, D1); D1 = fmaf(vb.y, f0.y, D1); D1 = fmaf(vb.z, f0.z, D1); D1 = fmaf(vb.w, f0.w, D1);
        va = xa[c*4+1]; vb = xb[c*4+1];
        D0 = fmaf(va.x, f1.x, D0); D0 = fmaf(va.y, f1.y, D0); D0 = fmaf(va.z, f1.z, D0); D0 = fmaf(va.w, f1.w, D0);
        D1 = fmaf(vb.x, f1.x, D1); D1 = fmaf(vb.y, f1.y, D1); D1 = fmaf(vb.z, f1.z, D1); D1 = fmaf(vb.w, f1.w, D1);
        va = xa[c*4+2]; vb = xb[c*4+2];
        D0 = fmaf(va.x, f2.x, D0); D0 = fmaf(va.y, f2.y, D0); D0 = fmaf(va.z, f2.z, D0); D0 = fmaf(va.w, f2.w, D0);
        D1 = fmaf(vb.x, f2.x, D1); D1 = fmaf(vb.y, f2.y, D1); D1 = fmaf(vb.z, f2.z, D1); D1 = fmaf(vb.w, f2.w, D1);
        va = xa[c*4+3]; vb = xb[c*4+3];
        D0 = fmaf(va.x, f3.x, D0); D0 = fmaf(va.y, f3.y, D0); D0 = fmaf(va.z, f3.z, D0); D0 = fmaf(va.w, f3.w, D0);
        D1 = fmaf(vb.x, f3.x, D1); D1 = fmaf(vb.y, f3.y, D1); D1 = fmaf(vb.z, f3.z, D1); D1 = fmaf(vb.w, f3.w, D1);
      }
      S.op[0][j] = D0; S.op[1][j] = D1;
    }
    __syncthreads();

    // PH7: comp2 partials — per elem, identical mapping to R5
    {
      int qd = sub & 3, nq = sub >> 2;   // nq 0..63
      #pragma unroll
      for (int p = 0; p < 2; ++p) {
        int n = p * 64 + nq;
        if (n < NNODE) {
          float acc = 0.f;
          #pragma unroll
          for (int i4 = 0; i4 < 8; ++i4) {
            float4 ov = *(const float4*)&S.op[e][qd * 32 + i4 * 4];
            float4 e4 = *(const float4*)&EL(e, n, qd * 32 + i4 * 4);
            acc = fmaf(e4.x, ov.x, acc);
            acc = fmaf(e4.y, ov.y, acc);
            acc = fmaf(e4.z, ov.z, acc);
            acc = fmaf(e4.w, ov.w, acc);
          }
          SRED(e, n, qd) = acc;
        }
      }
    }
    __syncthreads();
    // PH7b: logits
    if (sub < NNODE) {
      float4 r = *(const float4*)&SRED(e, sub, 0);
      float tot = (r.x + r.y) + (r.z + r.w);
      float x = tanhf(tot * NORM_PROB) * 10.f;
      S.c2[e][sub] = (S.mask[e][sub] > 0.5f) ? NEG_INF : x;
    }
    __syncthreads();

    // PH8: argmax + logsumexp + scalar state (waves 0 and 4)
    if (sub < 64) {
      int lane = sub;
      float v0 = S.c2[e][lane];
      float v1 = (lane < NNODE - 64) ? S.c2[e][lane + 64] : NEG_INF;
      float bv; int bi;
      if (v1 > v0) { bv = v1; bi = lane + 64; } else { bv = v0; bi = lane; }
      #pragma unroll
      for (int o = 32; o > 0; o >>= 1) {
        float ov = __shfl_xor(bv, o, 64);
        int   oi = __shfl_xor(bi, o, 64);
        if (ov > bv || (ov == bv && oi < bi)) { bv = ov; bi = oi; }
      }
      float e0 = expf(v0 - bv);
      float e1 = (lane < NNODE - 64) ? expf(v1 - bv) : 0.f;
      float ss = e0 + e1;
      #pragma unroll
      for (int o = 32; o > 0; o >>= 1) ss += __shfl_xor(ss, o, 64);
      int c = 0;
      if (lane >= 1 && S.mask1[e][lane] > 0.5f) c++;
      if (lane + 64 < NNODE && S.mask1[e][lane + 64] > 0.5f) c++;
      #pragma unroll
      for (int o = 32; o > 0; o >>= 1) c += __shfl_xor(c, o, 64);
      if (lane == 0) {
        if (c < NNODE - 1) S.lp[e] += -logf(ss);
        d_out[(size_t)myb * NSTEP + step] = (float)bi;
        S.cap[e] = (bi < 1) ? cap0 : (S.cap[e] - S.dem[e][bi]);
        S.idx[e] = bi;
      }
    }
    __syncthreads();

    // PH9: new input row + mask/mask1 update with NEW cap
    {
      int idx = S.idx[e];
      if (sub < 128) S.in_[e][sub] = EL(e, idx, sub);
      if (sub < NNODE) {
        float v1;
        if (sub == 0) v1 = (idx < 1) ? 1.f : 0.f;
        else          v1 = (sub == idx) ? 1.f : S.mask1[e][sub];
        S.mask1[e][sub] = v1;
        S.mask[e][sub] = (S.dem[e][sub] > S.cap[e]) ? 1.f : v1;
      }
      __syncthreads();
      if (sub < 64) {
        bool ok = (sub == 0) || (S.mask[e][sub] > 0.5f);
        if (sub + 64 < NNODE) ok = ok && (S.mask[e][sub + 64] > 0.5f);
        bool alld = __all(ok);
        if (alld && sub == 0) S.mask[e][0] = 0.f;
      }
      __syncthreads();
    }
  }

  if (sub == 0) d_out[(size_t)BTOT * NSTEP + myb] = S.lp[e];
}

extern "C" void kernel_launch(void* const* d_in, const int* in_sizes, int n_in,
                              void* d_out, int out_size, void* d_ws, size_t ws_size,
                              hipStream_t stream) {
  const float* enc   = (const float*)d_in[0];
  const float* pool  = (const float*)d_in[1];
  const float* cap   = (const float*)d_in[2];
  const float* dem   = (const float*)d_in[3];
  const float* fc_w  = (const float*)d_in[7];
  const float* fc1_w = (const float*)d_in[8];
  const float* pk_w  = (const float*)d_in[9];
  const float* mw_w  = (const float*)d_in[10];
  const float* mk_w  = (const float*)d_in[11];
  const float* mv_w  = (const float*)d_in[12];
  const float* mfc_w = (const float*)d_in[13];
  float* out = (float*)d_out;
  float* ws  = (float*)d_ws;

  prep_weights<<<194, 256, 0, stream>>>(fc_w, mk_w, mfc_w, pk_w, ws);
  decoder_loop<<<BTOT / 2, 512, 0, stream>>>(enc, pool, cap, dem, fc1_w, mw_w, mv_w, ws, out);
}

// Round 7
// 14310.822 us; speedup vs baseline: 6.7281x; 6.7281x over previous
//
#include <hip/hip_runtime.h>

#define NNODE 101
#define DIM   128
#define NHEAD 8
#define NSTEP 150
#define BTOT  2048
#define ENCP  132          // padded enc row stride in LDS

#define OFF_MK  16896
#define OFF_FT  33280
#define NORM_PROB 0.08838834764831845f

// One block = one batch element, 256 threads (4 waves), enc slice in LDS.
// Weight reads are per-thread CONTIGUOUS float4 rows (original row-major layout),
// 4x fewer load insts + 4x memory-level parallelism vs R5's strided dword loads.
// All reduction chains keep R5's proven sequential order (bit-exact).
struct __align__(16) BS {
  float enc[NNODE * ENCP];   // 53328 B
  float in_[DIM];
  float pl[DIM];
  float dec[DIM];            // holds a_fc; PH2 adds pl inline (same float value)
  float q[DIM];
  float attn[DIM];
  float op[DIM];
  float U[2112];             // QK/ZR: h*132+i ; CMP: 1056+h*104+n
  float sc[1212];            // SC: n*12+h ; SRED: n*12+k
  float c2[NNODE];
  float mask[NNODE];
  float mask1[NNODE];
  float dem[NNODE];
  float cap;
  float lp;
  int   idx;
};

#define EL(n,i)     S.enc[(n)*ENCP + (i)]
#define QK(h,i)     S.U[(h)*132 + (i)]
#define ZR(h,i)     S.U[(h)*132 + (i)]
#define CMP(h,n)    S.U[1056 + (h)*104 + (n)]
#define SC(n,h)     S.sc[(n)*12 + (h)]
#define SRED(n,k)   S.sc[(n)*12 + (k)]

// ws: [0,16896) fc rows padded to 132 (16B-aligned rows);
// [OFF_MK,+16384) mk repacked (h*128+j)*16+k (contig 16 per (h,j));
// [OFF_FT,+16384) F^T rows: ws[OFF_FT + j*128 + i2] = sum_d mfc[d][i2]*pk[d][j]
__global__ void prep_weights(const float* __restrict__ fc_w,
                             const float* __restrict__ mk_w,
                             const float* __restrict__ mfc_w,
                             const float* __restrict__ pk_w,
                             float* __restrict__ ws) {
  int x = blockIdx.x * 256 + threadIdx.x;
  if (x < 16896) {
    int jj = x / 132, i = x - jj * 132;
    ws[x] = (i < 129) ? fc_w[jj * 129 + i] : 0.f;
    return;
  }
  x -= 16896;
  if (x < 16384) {
    int h = x >> 11, r = x & 2047, jj = r >> 4, k = r & 15;
    ws[OFF_MK + x] = mk_w[(h * 16 + k) * 128 + jj];
    return;
  }
  x -= 16384;
  if (x < 16384) {
    int jj = x >> 7, i2 = x & 127;
    float acc = 0.f;
    for (int d = 0; d < 128; ++d)
      acc = fmaf(mfc_w[d * 128 + i2], pk_w[d * 128 + jj], acc);
    ws[OFF_FT + x] = acc;
  }
}

__global__ __launch_bounds__(256, 2) void decoder_loop(
    const float* __restrict__ enc, const float* __restrict__ pool,
    const float* __restrict__ capcity, const float* __restrict__ demand,
    const float* __restrict__ fc1_w, const float* __restrict__ mw_w,
    const float* __restrict__ mv_w,
    const float* __restrict__ ws, float* __restrict__ d_out) {
  __shared__ BS S;

  const int tl   = threadIdx.x;        // 0..255
  const int j    = tl & 127;
  const int half = tl >> 7;            // wave-uniform
  const int b    = blockIdx.x;
  const size_t encB = (size_t)b * NNODE * DIM;
  const float NEG_INF = -__builtin_inff();
  const float cap0 = capcity[0];

  // ---- stage enc slice into LDS (padded rows), coalesced float4 ----
  for (int x = tl; x < NNODE * 32; x += 256) {
    int n = x >> 5, c = x & 31;
    float4 v = *(const float4*)(enc + encB + (size_t)n * DIM + c * 4);
    *(float4*)&EL(n, c * 4) = v;
  }
  __syncthreads();

  // ---- init carry ----
  if (tl < 128) {
    S.in_[tl] = EL(0, tl);                             // input0 = enc[b,0,:]
    S.pl[tl]  = pool[(size_t)b * DIM + tl];
  }
  if (tl < NNODE) {
    S.dem[tl]   = demand[(size_t)b * NNODE + tl];
    S.mask1[tl] = 0.f;
  }
  if (tl == 0) { S.cap = capcity[b]; S.lp = 0.f; S.idx = 0; }
  __syncthreads();
  // mask_update(cap, idx=0)
  {
    if (tl < NNODE) {
      float v1 = (tl == 0) ? 1.f : 0.f;
      S.mask1[tl] = v1;
      S.mask[tl] = (S.dem[tl] > S.cap) ? 1.f : v1;
    }
    __syncthreads();
    if (tl < 64) {
      bool ok = (tl == 0) || (S.mask[tl] > 0.5f);
      if (tl + 64 < NNODE) ok = ok && (S.mask[tl + 64] > 0.5f);
      bool alld = __all(ok);
      if (alld && tl == 0) S.mask[0] = 0.f;
    }
    __syncthreads();
  }

  for (int step = 0; step < NSTEP; ++step) {
    const float cap = S.cap;

    // PH1: waves 0-1: a_fc chain (fc rows from ws, contiguous); waves 2-3: a_pl (fc1 rows).
    {
      float a = 0.f;
      if (half == 0) {
        const float4* x4 = (const float4*)&S.in_[0];
        const float4* w4 = (const float4*)(ws + (size_t)j * 132);
        #pragma unroll 8
        for (int t = 0; t < 32; ++t) {
          float4 xv = x4[t], wv = w4[t];
          a = fmaf(xv.x, wv.x, a);
          a = fmaf(xv.y, wv.y, a);
          a = fmaf(xv.z, wv.z, a);
          a = fmaf(xv.w, wv.w, a);
        }
        a = fmaf(cap, ws[(size_t)j * 132 + 128], a);
      } else {
        const float4* p4 = (const float4*)&S.pl[0];
        const float4* w4 = (const float4*)(fc1_w + (size_t)j * 128);
        #pragma unroll 8
        for (int t = 0; t < 32; ++t) {
          float4 pv = p4[t], wv = w4[t];
          a = fmaf(pv.x, wv.x, a);
          a = fmaf(pv.y, wv.y, a);
          a = fmaf(pv.z, wv.z, a);
          a = fmaf(pv.w, wv.w, a);
        }
      }
      __syncthreads();
      if (half == 0) S.dec[j] = a; else S.pl[j] = a;
    }
    __syncthreads();

    // PH2: Q = (dec+pl) @ mw^T — mw row j contiguous
    if (half == 0) {
      const float4* x4 = (const float4*)&S.dec[0];
      const float4* p4 = (const float4*)&S.pl[0];
      const float4* w4 = (const float4*)(mw_w + (size_t)j * 128);
      float acc = 0.f;
      #pragma unroll 8
      for (int t = 0; t < 32; ++t) {
        float4 xv = x4[t], pv = p4[t], wv = w4[t];
        acc = fmaf(xv.x + pv.x, wv.x, acc);
        acc = fmaf(xv.y + pv.y, wv.y, acc);
        acc = fmaf(xv.z + pv.z, wv.z, acc);
        acc = fmaf(xv.w + pv.w, wv.w, acc);
      }
      S.q[j] = acc;
    }
    __syncthreads();

    // PH2b: qk[h][j], 4 heads per thread (hb = half*4); mk contiguous 16 per (h,j)
    {
      const float4* q4 = (const float4*)&S.q[0];
      int hb = half * 4;
      #pragma unroll
      for (int hh = 0; hh < 4; ++hh) {
        int h = hb + hh;
        float4 qa = q4[h * 4 + 0], qb = q4[h * 4 + 1], qc = q4[h * 4 + 2], qd4 = q4[h * 4 + 3];
        const float4* m4 = (const float4*)(ws + OFF_MK + (size_t)(h * 128 + j) * 16);
        float4 m0 = m4[0], m1 = m4[1], m2 = m4[2], m3 = m4[3];
        float acc = 0.f;
        acc = fmaf(qa.x,  m0.x, acc); acc = fmaf(qa.y,  m0.y, acc);
        acc = fmaf(qa.z,  m0.z, acc); acc = fmaf(qa.w,  m0.w, acc);
        acc = fmaf(qb.x,  m1.x, acc); acc = fmaf(qb.y,  m1.y, acc);
        acc = fmaf(qb.z,  m1.z, acc); acc = fmaf(qb.w,  m1.w, acc);
        acc = fmaf(qc.x,  m2.x, acc); acc = fmaf(qc.y,  m2.y, acc);
        acc = fmaf(qc.z,  m2.z, acc); acc = fmaf(qc.w,  m2.w, acc);
        acc = fmaf(qd4.x, m3.x, acc); acc = fmaf(qd4.y, m3.y, acc);
        acc = fmaf(qd4.z, m3.z, acc); acc = fmaf(qd4.w, m3.w, acc);
        QK(h, j) = acc;
      }
    }
    __syncthreads();

    // PH3: comp[h][n] = 0.25 * enc[n].qk[h]  (mapping identical to R5)
    {
      int h = tl & 7, nb = tl >> 3;       // nb in 0..31
      float acc[4] = {0.f, 0.f, 0.f, 0.f};
      for (int i4 = 0; i4 < 32; ++i4) {
        float4 qv = *(const float4*)&QK(h, i4 * 4);
        #pragma unroll
        for (int p = 0; p < 4; ++p) {
          int n = p * 32 + nb;
          if (n < NNODE) {
            float4 e4 = *(const float4*)&EL(n, i4 * 4);
            acc[p] = fmaf(e4.x, qv.x, acc[p]);
            acc[p] = fmaf(e4.y, qv.y, acc[p]);
            acc[p] = fmaf(e4.z, qv.z, acc[p]);
            acc[p] = fmaf(e4.w, qv.w, acc[p]);
          }
        }
      }
      #pragma unroll
      for (int p = 0; p < 4; ++p) {
        int n = p * 32 + nb;
        if (n < NNODE)
          CMP(h, n) = (S.mask[n] > 0.5f) ? NEG_INF : 0.25f * acc[p];
      }
    }
    __syncthreads();

    // PH4: softmax rows; 4 waves x 2 heads; write transposed sc[n][h]
    {
      int w = tl >> 6, lane = tl & 63;
      int hb = w * 2;
      #pragma unroll
      for (int hh = 0; hh < 2; ++hh) {
        int h = hb + hh;
        float v0 = CMP(h, lane);
        float v1 = (lane < NNODE - 64) ? CMP(h, lane + 64) : NEG_INF;
        float m = fmaxf(v0, v1);
        #pragma unroll
        for (int o = 32; o > 0; o >>= 1) m = fmaxf(m, __shfl_xor(m, o, 64));
        float e0 = expf(v0 - m);
        float e1 = (lane < NNODE - 64) ? expf(v1 - m) : 0.f;
        float ss = e0 + e1;
        #pragma unroll
        for (int o = 32; o > 0; o >>= 1) ss += __shfl_xor(ss, o, 64);
        SC(lane, h) = e0 / ss;
        if (lane < NNODE - 64) SC(lane + 64, h) = e1 / ss;
      }
    }
    __syncthreads();

    // PH5: z[h][j] = sum_n sc[n][h]*enc[n][j] — 4 heads per thread (by half)
    {
      int hb = half * 4;
      float acc[4] = {0.f, 0.f, 0.f, 0.f};
      #pragma unroll 4
      for (int n = 0; n < NNODE; ++n) {
        float4 s = *(const float4*)&SC(n, hb);
        float ev = EL(n, j);
        acc[0] = fmaf(s.x, ev, acc[0]);
        acc[1] = fmaf(s.y, ev, acc[1]);
        acc[2] = fmaf(s.z, ev, acc[2]);
        acc[3] = fmaf(s.w, ev, acc[3]);
      }
      #pragma unroll
      for (int hh = 0; hh < 4; ++hh) ZR(hb + hh, j) = acc[hh];
    }
    __syncthreads();

    // PH5b: attn[j] = sum_i z[h(j)][i] * mv_w[j][i] — mv row j contiguous
    if (half == 0) {
      int h = j >> 4;
      const float4* w4 = (const float4*)(mv_w + (size_t)j * 128);
      float acc = 0.f;
      #pragma unroll 8
      for (int t = 0; t < 32; ++t) {
        float4 zv = *(const float4*)&ZR(h, t * 4);
        float4 wv = w4[t];
        acc = fmaf(zv.x, wv.x, acc);
        acc = fmaf(zv.y, wv.y, acc);
        acc = fmaf(zv.z, wv.z, acc);
        acc = fmaf(zv.w, wv.w, acc);
      }
      S.attn[j] = acc;
    }
    __syncthreads();

    // PH6: op[j] = sum_i2 attn[i2] * F[i2][j] — F^T row j contiguous
    if (half == 0) {
      const float4* x4 = (const float4*)&S.attn[0];
      const float4* w4 = (const float4*)(ws + OFF_FT + (size_t)j * 128);
      float acc = 0.f;
      #pragma unroll 8
      for (int t = 0; t < 32; ++t) {
        float4 xv = x4[t], wv = w4[t];
        acc = fmaf(xv.x, wv.x, acc);
        acc = fmaf(xv.y, wv.y, acc);
        acc = fmaf(xv.z, wv.z, acc);
        acc = fmaf(xv.w, wv.w, acc);
      }
      S.op[j] = acc;
    }
    __syncthreads();

    // PH7: comp2[n] = enc[n].op — 4-way dim split (mapping identical to R5)
    {
      int qd = tl & 3, nq = tl >> 2;       // nq 0..63
      #pragma unroll
      for (int p = 0; p < 2; ++p) {
        int n = p * 64 + nq;
        if (n < NNODE) {
          float acc = 0.f;
          #pragma unroll
          for (int i4 = 0; i4 < 8; ++i4) {
            float4 ov = *(const float4*)&S.op[qd * 32 + i4 * 4];
            float4 e4 = *(const float4*)&EL(n, qd * 32 + i4 * 4);
            acc = fmaf(e4.x, ov.x, acc);
            acc = fmaf(e4.y, ov.y, acc);
            acc = fmaf(e4.z, ov.z, acc);
            acc = fmaf(e4.w, ov.w, acc);
          }
          SRED(n, qd) = acc;
        }
      }
    }
    __syncthreads();
    // PH7b: logits
    if (tl < NNODE) {
      float4 r = *(const float4*)&SRED(tl, 0);
      float tot = (r.x + r.y) + (r.z + r.w);
      float x = tanhf(tot * NORM_PROB) * 10.f;
      S.c2[tl] = (S.mask[tl] > 0.5f) ? NEG_INF : x;
    }
    __syncthreads();

    // PH8: argmax (first-index ties) + logsumexp + scalar state update (wave 0)
    if (tl < 64) {
      int lane = tl;
      float v0 = S.c2[lane];
      float v1 = (lane < NNODE - 64) ? S.c2[lane + 64] : NEG_INF;
      float bv; int bi;
      if (v1 > v0) { bv = v1; bi = lane + 64; } else { bv = v0; bi = lane; }
      #pragma unroll
      for (int o = 32; o > 0; o >>= 1) {
        float ov = __shfl_xor(bv, o, 64);
        int   oi = __shfl_xor(bi, o, 64);
        if (ov > bv || (ov == bv && oi < bi)) { bv = ov; bi = oi; }
      }
      float e0 = expf(v0 - bv);
      float e1 = (lane < NNODE - 64) ? expf(v1 - bv) : 0.f;
      float ss = e0 + e1;
      #pragma unroll
      for (int o = 32; o > 0; o >>= 1) ss += __shfl_xor(ss, o, 64);
      int c = 0;
      if (lane >= 1 && S.mask1[lane] > 0.5f) c++;
      if (lane + 64 < NNODE && S.mask1[lane + 64] > 0.5f) c++;
      #pragma unroll
      for (int o = 32; o > 0; o >>= 1) c += __shfl_xor(c, o, 64);
      if (lane == 0) {
        if (c < NNODE - 1) S.lp += -logf(ss);             // is_done gating (pre-update mask1)
        d_out[(size_t)b * NSTEP + step] = (float)bi;
        S.cap = (bi < 1) ? cap0 : (S.cap - S.dem[bi]);
        S.idx = bi;
      }
    }
    __syncthreads();

    // PH9: new input row (from LDS) + mask/mask1 update with NEW cap
    {
      int idx = S.idx;
      if (tl < 128) S.in_[tl] = EL(idx, tl);
      if (tl < NNODE) {
        float v1;
        if (tl == 0) v1 = (idx < 1) ? 1.f : 0.f;          // mask1[:, :nd] rule (nd=1)
        else         v1 = (tl == idx) ? 1.f : S.mask1[tl];
        S.mask1[tl] = v1;
        S.mask[tl] = (S.dem[tl] > S.cap) ? 1.f : v1;
      }
      __syncthreads();
      if (tl < 64) {
        bool ok = (tl == 0) || (S.mask[tl] > 0.5f);
        if (tl + 64 < NNODE) ok = ok && (S.mask[tl + 64] > 0.5f);
        bool alld = __all(ok);
        if (alld && tl == 0) S.mask[0] = 0.f;             // reopen depot when all done
      }
      __syncthreads();
    }
  }

  if (tl == 0) d_out[(size_t)BTOT * NSTEP + b] = S.lp;
}

extern "C" void kernel_launch(void* const* d_in, const int* in_sizes, int n_in,
                              void* d_out, int out_size, void* d_ws, size_t ws_size,
                              hipStream_t stream) {
  const float* enc   = (const float*)d_in[0];
  const float* pool  = (const float*)d_in[1];
  const float* cap   = (const float*)d_in[2];
  const float* dem   = (const float*)d_in[3];
  const float* fc_w  = (const float*)d_in[7];
  const float* fc1_w = (const float*)d_in[8];
  const float* pk_w  = (const float*)d_in[9];
  const float* mw_w  = (const float*)d_in[10];
  const float* mk_w  = (const float*)d_in[11];
  const float* mv_w  = (const float*)d_in[12];
  const float* mfc_w = (const float*)d_in[13];
  float* out = (float*)d_out;
  float* ws  = (float*)d_ws;

  prep_weights<<<194, 256, 0, stream>>>(fc_w, mk_w, mfc_w, pk_w, ws);
  decoder_loop<<<BTOT, 256, 0, stream>>>(enc, pool, cap, dem, fc1_w, mw_w, mv_w, ws, out);
}

// Round 8
// 12353.180 us; speedup vs baseline: 7.7943x; 1.1585x over previous
//
#include <hip/hip_runtime.h>

#define NNODE 101
#define DIM   128
#define NHEAD 8
#define NSTEP 150
#define BTOT  2048
#define ENCP  132          // padded enc row stride in LDS

#define OFF_FCT  0
#define OFF_FC1T 16512
#define OFF_MWT  (OFF_FC1T + 16384)
#define OFF_MVT  (OFF_MWT + 16384)
#define OFF_F    (OFF_MVT + 16384)
#define NORM_PROB 0.08838834764831845f

// One block = TWO batch elements, 512 threads (8 waves), 1 block/CU (LDS 141 KB).
// Weight matvecs: lane-coalesced strided loads (R5-proven), ONE load feeding TWO
// accumulator chains (elem A, elem B) -> half the weight L2 traffic, 2x ILP.
// All reduction chains keep the proven sequential order (bit-exact).
struct __align__(16) BS {
  float enc[2][NNODE * ENCP];           // 2 x 53328 B
  float in_[2][DIM], pl[2][DIM], dec[2][DIM], q[2][DIM], attn[2][DIM], op[2][DIM];
  float U[2][1888];                     // QK/ZR: h*132+i ; CMP: 1056+h*104+n
  float sc[2][1212];                    // SC: n*12+h ; SRED: n*12+k
  float c2[2][NNODE];
  float mask[2][NNODE], mask1[2][NNODE], dem[2][NNODE];
  float cap[2], lp[2];
  int   idx[2];
};

#define EL(e,n,i)     S.enc[e][(n)*ENCP + (i)]
#define QK(e,h,i)     S.U[e][(h)*132 + (i)]
#define ZR(e,h,i)     S.U[e][(h)*132 + (i)]
#define CMP(e,h,n)    S.U[e][1056 + (h)*104 + (n)]
#define SC(e,n,h)     S.sc[e][(n)*12 + (h)]
#define SRED(e,n,k)   S.sc[e][(n)*12 + (k)]

// Transposed weights + fused F = mfc_w^T @ pk_w (R1-R5 proven layout)
__global__ void prep_weights(const float* __restrict__ fc_w,
                             const float* __restrict__ fc1_w,
                             const float* __restrict__ mw_w,
                             const float* __restrict__ mv_w,
                             const float* __restrict__ mfc_w,
                             const float* __restrict__ pk_w,
                             float* __restrict__ ws) {
  int x = blockIdx.x * 256 + threadIdx.x;
  if (x < 16512) { int i = x >> 7, j = x & 127; ws[OFF_FCT + x] = fc_w[j * 129 + i]; return; }
  x -= 16512;
  if (x < 16384) { int i = x >> 7, j = x & 127; ws[OFF_FC1T + x] = fc1_w[j * 128 + i]; return; }
  x -= 16384;
  if (x < 16384) { int i = x >> 7, j = x & 127; ws[OFF_MWT + x] = mw_w[j * 128 + i]; return; }
  x -= 16384;
  if (x < 16384) { int i = x >> 7, j = x & 127; ws[OFF_MVT + x] = mv_w[j * 128 + i]; return; }
  x -= 16384;
  if (x < 16384) {
    int i2 = x >> 7, i = x & 127;
    float acc = 0.f;
    for (int d = 0; d < 128; ++d)
      acc = fmaf(mfc_w[d * 128 + i2], pk_w[d * 128 + i], acc);
    ws[OFF_F + x] = acc;
  }
}

__global__ __launch_bounds__(512, 2) void decoder_loop(
    const float* __restrict__ enc, const float* __restrict__ pool,
    const float* __restrict__ capcity, const float* __restrict__ demand,
    const float* __restrict__ mk_w,
    const float* __restrict__ ws, float* __restrict__ d_out) {
  const float* fcT  = ws + OFF_FCT;
  const float* fc1T = ws + OFF_FC1T;
  const float* mwT  = ws + OFF_MWT;
  const float* mvT  = ws + OFF_MVT;
  const float* Fm   = ws + OFF_F;

  __shared__ BS S;

  const int tl   = threadIdx.x;       // 0..511
  const int j    = tl & 127;
  const int quad = tl >> 7;           // 0..3, wave-uniform
  const int e    = quad >> 1;         // elem for per-elem (enc) phases
  const int sub  = tl & 255;          // 0..255 within elem group
  const int b    = blockIdx.x;
  const int myb  = 2 * b + e;
  const float NEG_INF = -__builtin_inff();
  const float cap0 = capcity[0];

  // ---- stage both enc slices into LDS ----
  for (int ee = 0; ee < 2; ++ee) {
    const float* src = enc + (size_t)(2 * b + ee) * NNODE * DIM;
    for (int x = tl; x < NNODE * 32; x += 512) {
      int n = x >> 5, c = x & 31;
      *(float4*)&EL(ee, n, c * 4) = *(const float4*)(src + (size_t)n * DIM + c * 4);
    }
  }
  __syncthreads();

  // ---- init carry ----
  if (sub < 128) {
    S.in_[e][sub] = EL(e, 0, sub);
    S.pl[e][sub]  = pool[(size_t)myb * DIM + sub];
  }
  if (sub < NNODE) S.dem[e][sub] = demand[(size_t)myb * NNODE + sub];
  if (sub == 0) { S.cap[e] = capcity[myb]; S.lp[e] = 0.f; S.idx[e] = 0; }
  __syncthreads();
  if (sub < NNODE) {
    float v1 = (sub == 0) ? 1.f : 0.f;
    S.mask1[e][sub] = v1;
    S.mask[e][sub] = (S.dem[e][sub] > S.cap[e]) ? 1.f : v1;
  }
  __syncthreads();
  if (sub < 64) {                       // waves 0 (e0) and 4 (e1)
    bool ok = (sub == 0) || (S.mask[e][sub] > 0.5f);
    if (sub + 64 < NNODE) ok = ok && (S.mask[e][sub + 64] > 0.5f);
    bool alld = __all(ok);
    if (alld && sub == 0) S.mask[e][0] = 0.f;
  }
  __syncthreads();

  for (int step = 0; step < NSTEP; ++step) {
    const float capR0 = S.cap[0], capR1 = S.cap[1];

    // PH1: q0: fc chains (both elems); q1: fc1 chains (both elems). Strided coalesced loads.
    float A0 = 0.f, A1 = 0.f;
    if (quad == 0) {
      const float4* x0 = (const float4*)&S.in_[0][0];
      const float4* x1 = (const float4*)&S.in_[1][0];
      #pragma unroll 8
      for (int t = 0; t < 32; ++t) {
        float4 v0 = x0[t], v1 = x1[t];
        const float* wf = fcT + (t * 4) * DIM + j;
        float w0 = wf[0], w1 = wf[DIM], w2 = wf[2 * DIM], w3 = wf[3 * DIM];
        A0 = fmaf(v0.x, w0, A0); A0 = fmaf(v0.y, w1, A0);
        A0 = fmaf(v0.z, w2, A0); A0 = fmaf(v0.w, w3, A0);
        A1 = fmaf(v1.x, w0, A1); A1 = fmaf(v1.y, w1, A1);
        A1 = fmaf(v1.z, w2, A1); A1 = fmaf(v1.w, w3, A1);
      }
      float wc = fcT[DIM * DIM + j];
      A0 = fmaf(capR0, wc, A0);
      A1 = fmaf(capR1, wc, A1);
    } else if (quad == 1) {
      const float4* x0 = (const float4*)&S.pl[0][0];
      const float4* x1 = (const float4*)&S.pl[1][0];
      #pragma unroll 8
      for (int t = 0; t < 32; ++t) {
        float4 v0 = x0[t], v1 = x1[t];
        const float* wp = fc1T + (t * 4) * DIM + j;
        float w0 = wp[0], w1 = wp[DIM], w2 = wp[2 * DIM], w3 = wp[3 * DIM];
        A0 = fmaf(v0.x, w0, A0); A0 = fmaf(v0.y, w1, A0);
        A0 = fmaf(v0.z, w2, A0); A0 = fmaf(v0.w, w3, A0);
        A1 = fmaf(v1.x, w0, A1); A1 = fmaf(v1.y, w1, A1);
        A1 = fmaf(v1.z, w2, A1); A1 = fmaf(v1.w, w3, A1);
      }
    }
    __syncthreads();
    if (quad == 0)      { S.dec[0][j] = A0; S.dec[1][j] = A1; }
    else if (quad == 1) { S.pl[0][j]  = A0; S.pl[1][j]  = A1; }
    __syncthreads();

    // PH2: q2: Q = (dec+pl) @ mw^T, both elems (inline add = same float value)
    if (quad == 2) {
      const float4* d0 = (const float4*)&S.dec[0][0];
      const float4* p0 = (const float4*)&S.pl[0][0];
      const float4* d1 = (const float4*)&S.dec[1][0];
      const float4* p1 = (const float4*)&S.pl[1][0];
      float B0 = 0.f, B1 = 0.f;
      #pragma unroll 8
      for (int t = 0; t < 32; ++t) {
        float4 a0 = d0[t], b0 = p0[t], a1 = d1[t], b1 = p1[t];
        const float* w = mwT + (t * 4) * DIM + j;
        float w0 = w[0], w1 = w[DIM], w2 = w[2 * DIM], w3 = w[3 * DIM];
        B0 = fmaf(a0.x + b0.x, w0, B0); B0 = fmaf(a0.y + b0.y, w1, B0);
        B0 = fmaf(a0.z + b0.z, w2, B0); B0 = fmaf(a0.w + b0.w, w3, B0);
        B1 = fmaf(a1.x + b1.x, w0, B1); B1 = fmaf(a1.y + b1.y, w1, B1);
        B1 = fmaf(a1.z + b1.z, w2, B1); B1 = fmaf(a1.w + b1.w, w3, B1);
      }
      S.q[0][j] = B0; S.q[1][j] = B1;
    }
    __syncthreads();

    // PH2b: quad -> heads {2q, 2q+1}; each thread computes BOTH elems per head.
    // mk read once per block-step, lane-coalesced strided. Chain = k ascending (bit-exact).
    {
      const float4* q40 = (const float4*)&S.q[0][0];
      const float4* q41 = (const float4*)&S.q[1][0];
      #pragma unroll
      for (int hh = 0; hh < 2; ++hh) {
        int h = quad * 2 + hh;
        const float* w = mk_w + (h * 16) * DIM + j;
        float m0 = w[0],        m1 = w[DIM],      m2 = w[2 * DIM],  m3 = w[3 * DIM];
        float m4 = w[4 * DIM],  m5 = w[5 * DIM],  m6 = w[6 * DIM],  m7 = w[7 * DIM];
        float m8 = w[8 * DIM],  m9 = w[9 * DIM],  m10 = w[10 * DIM], m11 = w[11 * DIM];
        float m12 = w[12 * DIM], m13 = w[13 * DIM], m14 = w[14 * DIM], m15 = w[15 * DIM];
        float4 qa0 = q40[h*4], qb0 = q40[h*4+1], qc0 = q40[h*4+2], qd0 = q40[h*4+3];
        float4 qa1 = q41[h*4], qb1 = q41[h*4+1], qc1 = q41[h*4+2], qd1 = q41[h*4+3];
        float acc0 = 0.f, acc1 = 0.f;
        acc0 = fmaf(qa0.x, m0,  acc0); acc0 = fmaf(qa0.y, m1,  acc0);
        acc0 = fmaf(qa0.z, m2,  acc0); acc0 = fmaf(qa0.w, m3,  acc0);
        acc0 = fmaf(qb0.x, m4,  acc0); acc0 = fmaf(qb0.y, m5,  acc0);
        acc0 = fmaf(qb0.z, m6,  acc0); acc0 = fmaf(qb0.w, m7,  acc0);
        acc0 = fmaf(qc0.x, m8,  acc0); acc0 = fmaf(qc0.y, m9,  acc0);
        acc0 = fmaf(qc0.z, m10, acc0); acc0 = fmaf(qc0.w, m11, acc0);
        acc0 = fmaf(qd0.x, m12, acc0); acc0 = fmaf(qd0.y, m13, acc0);
        acc0 = fmaf(qd0.z, m14, acc0); acc0 = fmaf(qd0.w, m15, acc0);
        acc1 = fmaf(qa1.x, m0,  acc1); acc1 = fmaf(qa1.y, m1,  acc1);
        acc1 = fmaf(qa1.z, m2,  acc1); acc1 = fmaf(qa1.w, m3,  acc1);
        acc1 = fmaf(qb1.x, m4,  acc1); acc1 = fmaf(qb1.y, m5,  acc1);
        acc1 = fmaf(qb1.z, m6,  acc1); acc1 = fmaf(qb1.w, m7,  acc1);
        acc1 = fmaf(qc1.x, m8,  acc1); acc1 = fmaf(qc1.y, m9,  acc1);
        acc1 = fmaf(qc1.z, m10, acc1); acc1 = fmaf(qc1.w, m11, acc1);
        acc1 = fmaf(qd1.x, m12, acc1); acc1 = fmaf(qd1.y, m13, acc1);
        acc1 = fmaf(qd1.z, m14, acc1); acc1 = fmaf(qd1.w, m15, acc1);
        QK(0, h, j) = acc0;
        QK(1, h, j) = acc1;
      }
    }
    __syncthreads();

    // PH3: comp[h][n] = 0.25 * enc[n].qk[h]  (per-elem mapping, bit-exact)
    {
      int h = sub & 7, nb = sub >> 3;   // nb 0..31
      float acc[4] = {0.f, 0.f, 0.f, 0.f};
      for (int i4 = 0; i4 < 32; ++i4) {
        float4 qv = *(const float4*)&QK(e, h, i4 * 4);
        #pragma unroll
        for (int p = 0; p < 4; ++p) {
          int n = p * 32 + nb;
          if (n < NNODE) {
            float4 e4 = *(const float4*)&EL(e, n, i4 * 4);
            acc[p] = fmaf(e4.x, qv.x, acc[p]);
            acc[p] = fmaf(e4.y, qv.y, acc[p]);
            acc[p] = fmaf(e4.z, qv.z, acc[p]);
            acc[p] = fmaf(e4.w, qv.w, acc[p]);
          }
        }
      }
      #pragma unroll
      for (int p = 0; p < 4; ++p) {
        int n = p * 32 + nb;
        if (n < NNODE)
          CMP(e, h, n) = (S.mask[e][n] > 0.5f) ? NEG_INF : 0.25f * acc[p];
      }
    }
    __syncthreads();

    // PH4: softmax; 8 waves = (elem, head pair)
    {
      int w = tl >> 6, lane = tl & 63;
      int ee = w >> 2, hb = (w & 3) * 2;
      #pragma unroll
      for (int hh = 0; hh < 2; ++hh) {
        int h = hb + hh;
        float v0 = CMP(ee, h, lane);
        float v1 = (lane < NNODE - 64) ? CMP(ee, h, lane + 64) : NEG_INF;
        float m = fmaxf(v0, v1);
        #pragma unroll
        for (int o = 32; o > 0; o >>= 1) m = fmaxf(m, __shfl_xor(m, o, 64));
        float e0 = expf(v0 - m);
        float e1 = (lane < NNODE - 64) ? expf(v1 - m) : 0.f;
        float ss = e0 + e1;
        #pragma unroll
        for (int o = 32; o > 0; o >>= 1) ss += __shfl_xor(ss, o, 64);
        SC(ee, lane, h) = e0 / ss;
        if (lane < NNODE - 64) SC(ee, lane + 64, h) = e1 / ss;
      }
    }
    __syncthreads();

    // PH5: z[h][j] = sum_n sc[n][h]*enc[n][j] — per elem, 4 heads per thread
    {
      int hb = (sub >> 7) * 4;
      float acc[4] = {0.f, 0.f, 0.f, 0.f};
      #pragma unroll 4
      for (int n = 0; n < NNODE; ++n) {
        float4 s = *(const float4*)&SC(e, n, hb);
        float ev = EL(e, n, j);
        acc[0] = fmaf(s.x, ev, acc[0]);
        acc[1] = fmaf(s.y, ev, acc[1]);
        acc[2] = fmaf(s.z, ev, acc[2]);
        acc[3] = fmaf(s.w, ev, acc[3]);
      }
      #pragma unroll
      for (int hh = 0; hh < 4; ++hh) ZR(e, hb + hh, j) = acc[hh];
    }
    __syncthreads();

    // PH5b: q3: attn chains (both elems), strided mvT loads
    if (quad == 3) {
      int h = j >> 4;
      float C0 = 0.f, C1 = 0.f;
      #pragma unroll 8
      for (int t = 0; t < 32; ++t) {
        float4 z0 = *(const float4*)&ZR(0, h, t * 4);
        float4 z1 = *(const float4*)&ZR(1, h, t * 4);
        const float* w = mvT + (t * 4) * DIM + j;
        float w0 = w[0], w1 = w[DIM], w2 = w[2 * DIM], w3 = w[3 * DIM];
        C0 = fmaf(z0.x, w0, C0); C0 = fmaf(z0.y, w1, C0);
        C0 = fmaf(z0.z, w2, C0); C0 = fmaf(z0.w, w3, C0);
        C1 = fmaf(z1.x, w0, C1); C1 = fmaf(z1.y, w1, C1);
        C1 = fmaf(z1.z, w2, C1); C1 = fmaf(z1.w, w3, C1);
      }
      S.attn[0][j] = C0; S.attn[1][j] = C1;
    }
    __syncthreads();

    // PH6: q1: op = attn @ F (both elems), strided Fm loads
    if (quad == 1) {
      const float4* xa = (const float4*)&S.attn[0][0];
      const float4* xb = (const float4*)&S.attn[1][0];
      float D0 = 0.f, D1 = 0.f;
      #pragma unroll 8
      for (int t = 0; t < 32; ++t) {
        float4 va = xa[t], vb = xb[t];
        const float* w = Fm + (t * 4) * DIM + j;
        float w0 = w[0], w1 = w[DIM], w2 = w[2 * DIM], w3 = w[3 * DIM];
        D0 = fmaf(va.x, w0, D0); D0 = fmaf(va.y, w1, D0);
        D0 = fmaf(va.z, w2, D0); D0 = fmaf(va.w, w3, D0);
        D1 = fmaf(vb.x, w0, D1); D1 = fmaf(vb.y, w1, D1);
        D1 = fmaf(vb.z, w2, D1); D1 = fmaf(vb.w, w3, D1);
      }
      S.op[0][j] = D0; S.op[1][j] = D1;
    }
    __syncthreads();

    // PH7: comp2 partials — per elem (bit-exact mapping)
    {
      int qd = sub & 3, nq = sub >> 2;   // nq 0..63
      #pragma unroll
      for (int p = 0; p < 2; ++p) {
        int n = p * 64 + nq;
        if (n < NNODE) {
          float acc = 0.f;
          #pragma unroll
          for (int i4 = 0; i4 < 8; ++i4) {
            float4 ov = *(const float4*)&S.op[e][qd * 32 + i4 * 4];
            float4 e4 = *(const float4*)&EL(e, n, qd * 32 + i4 * 4);
            acc = fmaf(e4.x, ov.x, acc);
            acc = fmaf(e4.y, ov.y, acc);
            acc = fmaf(e4.z, ov.z, acc);
            acc = fmaf(e4.w, ov.w, acc);
          }
          SRED(e, n, qd) = acc;
        }
      }
    }
    __syncthreads();
    // PH7b: logits
    if (sub < NNODE) {
      float4 r = *(const float4*)&SRED(e, sub, 0);
      float tot = (r.x + r.y) + (r.z + r.w);
      float x = tanhf(tot * NORM_PROB) * 10.f;
      S.c2[e][sub] = (S.mask[e][sub] > 0.5f) ? NEG_INF : x;
    }
    __syncthreads();

    // PH8: argmax + logsumexp + scalar state (waves 0 and 4)
    if (sub < 64) {
      int lane = sub;
      float v0 = S.c2[e][lane];
      float v1 = (lane < NNODE - 64) ? S.c2[e][lane + 64] : NEG_INF;
      float bv; int bi;
      if (v1 > v0) { bv = v1; bi = lane + 64; } else { bv = v0; bi = lane; }
      #pragma unroll
      for (int o = 32; o > 0; o >>= 1) {
        float ov = __shfl_xor(bv, o, 64);
        int   oi = __shfl_xor(bi, o, 64);
        if (ov > bv || (ov == bv && oi < bi)) { bv = ov; bi = oi; }
      }
      float e0 = expf(v0 - bv);
      float e1 = (lane < NNODE - 64) ? expf(v1 - bv) : 0.f;
      float ss = e0 + e1;
      #pragma unroll
      for (int o = 32; o > 0; o >>= 1) ss += __shfl_xor(ss, o, 64);
      int c = 0;
      if (lane >= 1 && S.mask1[e][lane] > 0.5f) c++;
      if (lane + 64 < NNODE && S.mask1[e][lane + 64] > 0.5f) c++;
      #pragma unroll
      for (int o = 32; o > 0; o >>= 1) c += __shfl_xor(c, o, 64);
      if (lane == 0) {
        if (c < NNODE - 1) S.lp[e] += -logf(ss);
        d_out[(size_t)myb * NSTEP + step] = (float)bi;
        S.cap[e] = (bi < 1) ? cap0 : (S.cap[e] - S.dem[e][bi]);
        S.idx[e] = bi;
      }
    }
    __syncthreads();

    // PH9: new input row + mask/mask1 update with NEW cap
    {
      int idx = S.idx[e];
      if (sub < 128) S.in_[e][sub] = EL(e, idx, sub);
      if (sub < NNODE) {
        float v1;
        if (sub == 0) v1 = (idx < 1) ? 1.f : 0.f;
        else          v1 = (sub == idx) ? 1.f : S.mask1[e][sub];
        S.mask1[e][sub] = v1;
        S.mask[e][sub] = (S.dem[e][sub] > S.cap[e]) ? 1.f : v1;
      }
      __syncthreads();
      if (sub < 64) {
        bool ok = (sub == 0) || (S.mask[e][sub] > 0.5f);
        if (sub + 64 < NNODE) ok = ok && (S.mask[e][sub + 64] > 0.5f);
        bool alld = __all(ok);
        if (alld && sub == 0) S.mask[e][0] = 0.f;
      }
      __syncthreads();
    }
  }

  if (sub == 0) d_out[(size_t)BTOT * NSTEP + myb] = S.lp[e];
}

extern "C" void kernel_launch(void* const* d_in, const int* in_sizes, int n_in,
                              void* d_out, int out_size, void* d_ws, size_t ws_size,
                              hipStream_t stream) {
  const float* enc   = (const float*)d_in[0];
  const float* pool  = (const float*)d_in[1];
  const float* cap   = (const float*)d_in[2];
  const float* dem   = (const float*)d_in[3];
  const float* fc_w  = (const float*)d_in[7];
  const float* fc1_w = (const float*)d_in[8];
  const float* pk_w  = (const float*)d_in[9];
  const float* mw_w  = (const float*)d_in[10];
  const float* mk_w  = (const float*)d_in[11];
  const float* mv_w  = (const float*)d_in[12];
  const float* mfc_w = (const float*)d_in[13];
  float* out = (float*)d_out;
  float* ws  = (float*)d_ws;

  prep_weights<<<321, 256, 0, stream>>>(fc_w, fc1_w, mw_w, mv_w, mfc_w, pk_w, ws);
  decoder_loop<<<BTOT / 2, 512, 0, stream>>>(enc, pool, cap, dem, mk_w, ws, out);
}